// Round 8
// baseline (430.367 us; speedup 1.0000x reference)
//
#include <hip/hip_runtime.h>
#include <cstdint>
#include <cstddef>

constexpr int BB  = 32;
constexpr int TT  = 384;
constexpr int MM  = 1536;
constexpr int W32 = MM / 32;      // 48 bit-windows
constexpr int RPT = 6;            // rows per lane
constexpr float NEGV = -1.0e7f;

// workspace: bits[BB][W32][TT] + A[BB][512] + (optional) Tq[BB][MM][TT]
constexpr size_t WS_BITS_SZ = (size_t)BB * W32 * TT * 4;            // 2,359,296
constexpr size_t WS_A_OFF   = WS_BITS_SZ;
constexpr size_t WS_TQ_OFF  = WS_A_OFF + (size_t)BB * 512 * 4;      // 2,424,832
constexpr size_t WS_NEED    = WS_TQ_OFF + (size_t)BB * TT * MM * 4; // ~77.9 MB

// ---------------- tiled transpose: in [b][t][j] -> outT [b][j][t] (R3-proven) ----------------
__global__ __launch_bounds__(256) void mas_transpose(
    const float* __restrict__ in, float* __restrict__ outT)
{
  __shared__ float tile[32][33];
  const int b  = blockIdx.z;
  const int t0 = blockIdx.y * 32, j0 = blockIdx.x * 32;
  const int tx = threadIdx.x, ty = threadIdx.y;
  const float* ip = in  + (size_t)b * TT * MM;
  float*       op = outT + (size_t)b * TT * MM;
#pragma unroll
  for (int i = 0; i < 4; ++i)
    tile[ty + 8 * i][tx] = ip[(size_t)(t0 + ty + 8 * i) * MM + j0 + tx];
  __syncthreads();
#pragma unroll
  for (int i = 0; i < 4; ++i)
    op[(size_t)(j0 + ty + 8 * i) * TT + t0 + tx] = tile[tx][ty + 8 * i];
}

// ---------------- fused: DP+backtrack (blocks 0..31) + output zeroing (blocks 32+) ----------------
// mode 1: read transposed Tq[j][t] — coalesced column loads (3 float2/lane,
//         one addr reg + imm offsets), 8-slot ring, prefetch distance 6.
// mode 0: R6-proven direct path on log_p (fallback when ws too small).
// __launch_bounds__(64,1): min 1 wave/EU -> full VGPR budget (R3's ring was
// sunk because the default heuristic capped VGPRs for occupancy).
__global__ __launch_bounds__(64, 1) void mas_main(
    const float* __restrict__ Tq, const float* __restrict__ log_p,
    const float* __restrict__ mk0, uint32_t* __restrict__ bits,
    int* __restrict__ A, float* __restrict__ out, int mode)
{
  const int blk = blockIdx.x;
  const int k   = threadIdx.x;

  if (blk >= BB) {
    // ---- zero the 75.5 MB output while the DP runs (R7-proven overlap) ----
    float4 z; z.x = z.y = z.z = z.w = 0.0f;
    float4* o4 = (float4*)out;
    const int n4  = BB * TT * MM / 4;            // 4,718,592
    const int nth = (256 - BB) * 64;             // 14,336 threads
    for (int i = (blk - BB) * 64 + k; i < n4; i += nth) o4[i] = z;
    return;
  }

  // ================= DP + backtrack: sample b = blk =================
  const int b = blk;
  const float* mk = mk0 + (size_t)b * TT * MM;
  uint32_t* bitsS = bits + (size_t)b * W32 * TT;  // [window][row]
  int* Ab = A + b * 512;

  // ---- lengths from mask ----
  float ts = 0.f, ms = 0.f;
  for (int t = k; t < TT; t += 64) ts += mk[(size_t)t * MM];
  for (int j = k; j < MM; j += 64) ms += mk[j];
#pragma unroll
  for (int off = 32; off >= 1; off >>= 1) {
    ts += __shfl_xor(ts, off);
    ms += __shfl_xor(ms, off);
  }
  const int t_len = (int)ts;
  const int m_len = (int)ms;
  for (int t = k; t <= TT; t += 64) Ab[t] = (t >= t_len) ? m_len : 0;

  const int r0 = RPT * k;
  float    qp[RPT];
  uint32_t bacc[RPT];
#pragma unroll
  for (int i = 0; i < RPT; ++i) { qp[i] = NEGV; bacc[i] = 0u; }

  if (mode) {
    // ---- forward DP, transposed input: column j = Tp[j*TT + r0 .. +5] ----
    const float* Tp = Tq + (size_t)b * TT * MM;
    float2 rg[8][3];                  // 8-slot ring, prefetch distance 6
#pragma unroll
    for (int u = 0; u < 6; ++u) {     // prologue: cols 0..5 -> slots 0..5
      const float* p = Tp + (size_t)u * TT + r0;
      rg[u][0] = *(const float2*)p;
      rg[u][1] = *(const float2*)(p + 2);
      rg[u][2] = *(const float2*)(p + 4);
    }
    for (int w = 0; w < W32; ++w) {
#pragma unroll
      for (int u = 0; u < 32; ++u) {
        const int j = w * 32 + u;
        {  // prefetch col j+6 into slot (u+6)&7 (6 mod 8 != 0: never aliases u&7)
          int jp = j + 6; if (jp > MM - 1) jp = MM - 1;
          const float* p = Tp + (size_t)jp * TT + r0;
          const int s = (u + 6) & 7;
          rg[s][0] = *(const float2*)p;
          rg[s][1] = *(const float2*)(p + 2);
          rg[s][2] = *(const float2*)(p + 4);
        }
        const int cs = u & 7;
        const float x0 = rg[cs][0].x, x1 = rg[cs][0].y;
        const float x2 = rg[cs][1].x, x3 = rg[cs][1].y;
        const float x4 = rg[cs][2].x, x5 = rg[cs][2].y;
        const float sh = __shfl_up(qp[RPT - 1], 1);
        const float qlast = (k == 0) ? ((j == 0) ? 0.0f : NEGV) : sh;
        const uint32_t mbit = 1u << u;
#pragma unroll
        for (int i = RPT - 1; i >= 0; --i) {   // descending: qp[i-1] = prev col
          const float stay = qp[i];
          const float adv  = (i == 0) ? qlast : qp[i - 1];
          const float x = (i == 0) ? x0 : (i == 1) ? x1 : (i == 2) ? x2
                        : (i == 3) ? x3 : (i == 4) ? x4 : x5;
          qp[i] = x + fmaxf(stay, adv);
          if (stay < adv) bacc[i] |= mbit;
        }
      }
#pragma unroll
      for (int i = 0; i < RPT; ++i) { bitsS[w * TT + r0 + i] = bacc[i]; bacc[i] = 0u; }
    }
  } else {
    // ---- forward DP, direct input (R6-proven fallback) ----
    const float* lp = log_p + (size_t)b * TT * MM;
    float4 ring[4][RPT];
#pragma unroll
    for (int g = 0; g < 2; ++g)
#pragma unroll
      for (int i = 0; i < RPT; ++i)
        ring[g][i] = *(const float4*)(lp + (size_t)(r0 + i) * MM + g * 4);
    int j = 0;
    for (int w = 0; w < W32; ++w) {
#pragma unroll
      for (int g8 = 0; g8 < 8; ++g8) {
        {
          int gp = w * 8 + g8 + 2; if (gp > MM / 4 - 1) gp = MM / 4 - 1;
          const int pb = (g8 + 2) & 3;
#pragma unroll
          for (int i = 0; i < RPT; ++i)
            ring[pb][i] = *(const float4*)(lp + (size_t)(r0 + i) * MM + (size_t)gp * 4);
        }
        const int cb = g8 & 3;
#pragma unroll
        for (int u = 0; u < 4; ++u, ++j) {
          const float sh = __shfl_up(qp[RPT - 1], 1);
          const float qlast = (k == 0) ? ((j == 0) ? 0.0f : NEGV) : sh;
          const uint32_t mbit = 1u << (j & 31);
#pragma unroll
          for (int i = RPT - 1; i >= 0; --i) {
            const float stay = qp[i];
            const float adv  = (i == 0) ? qlast : qp[i - 1];
            const float x = (&ring[cb][i].x)[u];
            qp[i] = x + fmaxf(stay, adv);
            if (stay < adv) bacc[i] |= mbit;
          }
        }
      }
#pragma unroll
      for (int i = 0; i < RPT; ++i) { bitsS[w * TT + r0 + i] = bacc[i]; bacc[i] = 0u; }
    }
  }

  asm volatile("s_waitcnt vmcnt(0)" ::: "memory");   // own stores -> own loads

  // ---- backtrack (R3/R6-proven): lane L caches row (t_top - L)'s word ----
  int t = t_len - 1;
  int jj = m_len - 1;
  if (t <= 0 || jj < 1) return;
  int t_top = t;
  int w_cur = jj >> 5;
  uint32_t word;
  { const int row = t_top - k; word = (row >= 0) ? bitsS[w_cur * TT + row] : 0u; }

  for (int guard = 0; guard < 4096; ++guard) {
    const uint32_t cur = __shfl(word, t_top - t);
    const int bpos = jj & 31;
    uint32_t m = cur & ((bpos == 31) ? 0xffffffffu : ((2u << bpos) - 1u));
    if (w_cur == 0) m &= ~1u;
    if (m == 0u) {
      if (w_cur == 0) break;
      --w_cur; jj = (w_cur << 5) | 31;
      t_top = t;
      const int row = t_top - k;
      word = (row >= 0) ? bitsS[w_cur * TT + row] : 0u;
      continue;
    }
    const int p = 31 - __builtin_clz(m);
    jj = (w_cur << 5) | p;
    if (k == 0) Ab[t] = jj;
    --t; --jj;
    if (t <= 0 || jj < 1) break;
    const int wn = jj >> 5;
    if (wn != w_cur || (t_top - t) > 63) {
      w_cur = wn; t_top = t;
      const int row = t_top - k;
      word = (row >= 0) ? bitsS[w_cur * TT + row] : 0u;
    }
  }
}

// ---------------- sparse fill: write only the ones (R7-proven) ----------------
__global__ __launch_bounds__(64) void mas_ones(
    const int* __restrict__ A, float* __restrict__ out)
{
  const int b = blockIdx.x;
  const int k = threadIdx.x;
  const int* Ab = A + b * 512;
  float* ob = out + (size_t)b * TT * MM;
  for (int t = k; t < TT; t += 64) {
    const int a = Ab[t], e = Ab[t + 1];
    for (int j = a; j < e; ++j) ob[(size_t)t * MM + j] = 1.0f;
  }
}

extern "C" void kernel_launch(void* const* d_in, const int* in_sizes, int n_in,
                              void* d_out, int out_size, void* d_ws, size_t ws_size,
                              hipStream_t stream) {
  const float* log_p = (const float*)d_in[0];
  const float* maskp = (const float*)d_in[1];
  float* out = (float*)d_out;
  uint32_t* bits = (uint32_t*)d_ws;
  int* A = (int*)((char*)d_ws + WS_A_OFF);
  float* Tq = (float*)((char*)d_ws + WS_TQ_OFF);

  const int mode = (ws_size >= WS_NEED) ? 1 : 0;
  if (mode)
    mas_transpose<<<dim3(MM / 32, TT / 32, BB), dim3(32, 8), 0, stream>>>(log_p, Tq);
  mas_main<<<256, 64, 0, stream>>>(Tq, log_p, maskp, bits, A, out, mode);
  mas_ones<<<BB, 64, 0, stream>>>(A, out);
}